// Round 8
// baseline (870.087 us; speedup 1.0000x reference)
//
#include <hip/hip_runtime.h>
#include <cstdint>

#define H 256
#define NBMAX 400   // max coarse buckets per metapath (supports N <= 51200)
#define CAPB 16     // LDS slab slots per bucket (flush in groups of 8)

typedef unsigned short u16;
typedef __attribute__((ext_vector_type(8))) short short8;
typedef __attribute__((ext_vector_type(4))) float f32x4;

__device__ __forceinline__ float bf2f(u16 u) {
  return __uint_as_float(((unsigned)u) << 16);
}
__device__ __forceinline__ u16 f2bf(float f) {
  unsigned u = __float_as_uint(f);
  u = (u + 0x7FFF + ((u >> 16) & 1)) >> 16;   // RNE
  return (u16)u;
}
__device__ __forceinline__ void async16(const void* g, void* l) {
  __builtin_amdgcn_global_load_lds((const __attribute__((address_space(1))) void*)g,
                                   (__attribute__((address_space(3))) void*)l, 16, 0, 0);
}

// ---- fused prep: h->bf16 (both sides) + weights->bf16 + zero bcnt/sp ----
// grid (el_blocks, 3): y<2 = side conversion; y==2: x<384 weights, x==384 zeroing
__global__ __launch_bounds__(256) void prep(
    const float* __restrict__ h0, const float* __restrict__ h1,
    u16* __restrict__ hbf,
    const float* w0, const float* w1, const float* w2, const float* w3,
    const float* w4, const float* w5, u16* __restrict__ Wbf,
    int* __restrict__ bcnt, float* __restrict__ sp, int total, size_t NH)
{
  int y = blockIdx.y;
  int tid = threadIdx.x;
  if (y < 2) {
    const float* src = y ? h1 : h0;
    u16* d = hbf + (size_t)y * NH;
    int i = (blockIdx.x * 256 + tid) * 4;
    if (i >= total) return;
    float4 x = *(const float4*)(src + i);
    *(ushort4*)(d + i) = make_ushort4(f2bf(x.x), f2bf(x.y), f2bf(x.z), f2bf(x.w));
  } else {
    int x = blockIdx.x;
    if (x < 384) {
      const float* srcs[6] = {w0, w1, w2, w3, w4, w5};
      int m = x >> 6;
      int i = ((x & 63) * 256 + tid) * 4;
      float4 v = *(const float4*)(srcs[m] + i);
      *(ushort4*)(Wbf + (size_t)m * (H * H) + i) =
          make_ushort4(f2bf(v.x), f2bf(v.y), f2bf(v.z), f2bf(v.w));
    } else if (x == 384) {
      for (int i = tid; i < 4 * NBMAX; i += 256) bcnt[i] = 0;
      for (int i = tid; i < 4 * H; i += 256) sp[i] = 0.f;
    }
  }
}

__device__ __forceinline__ int block_incl_scan(int v) {
  __shared__ int wsum[4];
  int tid = threadIdx.x, lane = tid & 63, w = tid >> 6;
  int x = v;
  #pragma unroll
  for (int off = 1; off < 64; off <<= 1) {
    int n = __shfl_up(x, off);
    if (lane >= off) x += n;
  }
  if (lane == 63) wsum[w] = x;
  __syncthreads();
  int add = 0;
  #pragma unroll
  for (int i = 0; i < 4; ++i) add += (i < w) ? wsum[i] : 0;
  return x + add;
}

// ============ Bucketed CSR build (bucket = 128 consecutive dsts) =============
__global__ __launch_bounds__(1024) void hist_coarse(
    const int* i0, const int* i1, const int* i2, const int* i3,
    int* __restrict__ bcnt, int E, int nbuck)
{
  int mp = blockIdx.y;
  const int* idxs[4] = {i0, i1, i2, i3};
  const int* idx = idxs[mp];
  __shared__ int lh[NBMAX];
  int t = threadIdx.x;
  for (int i = t; i < nbuck; i += 1024) lh[i] = 0;
  __syncthreads();
  for (int e = blockIdx.x * 1024 + t; e < E; e += gridDim.x * 1024)
    atomicAdd(&lh[idx[e] >> 7], 1);
  __syncthreads();
  for (int i = t; i < nbuck; i += 1024) {
    int v = lh[i];
    if (v) atomicAdd(&bcnt[mp * nbuck + i], v);
  }
}

__global__ __launch_bounds__(256) void scan_buckets(
    const int* __restrict__ bcnt, int* __restrict__ bbase,
    int* __restrict__ gcur, int* __restrict__ rowptr, int N, int E, int nbuck)
{
  int mp = blockIdx.y;
  int t = threadIdx.x;
  int i0 = t * 2, i1 = t * 2 + 1;
  int a = (i0 < nbuck) ? bcnt[mp * nbuck + i0] : 0;
  int b = (i1 < nbuck) ? bcnt[mp * nbuck + i1] : 0;
  int s = a + b;
  int incl = block_incl_scan(s);
  int ex = incl - s;
  if (i0 < nbuck) { bbase[mp * nbuck + i0] = ex;     gcur[mp * nbuck + i0] = ex; }
  if (i1 < nbuck) { bbase[mp * nbuck + i1] = ex + a; gcur[mp * nbuck + i1] = ex + a; }
  if (t == 0) rowptr[mp * (N + 1) + N] = E;
}

// Stage 3: LDS write-combining scatter into bucket-contiguous staging.
__global__ __launch_bounds__(1024) void scatter_binned(
    const int* i0, const int* i1, const int* i2, const int* i3,
    const float* v0, const float* v1, const float* v2, const float* v3,
    int* __restrict__ gcur, int2* __restrict__ edgesB, int E, int nbuck)
{
  int mp = blockIdx.y;
  const int* idxs[4] = {i0, i1, i2, i3};
  const float* vals[4] = {v0, v1, v2, v3};
  const int* idx = idxs[mp];
  const float* val = vals[mp];
  int* cur = gcur + mp * nbuck;
  int2* out = edgesB + (size_t)mp * E;

  __shared__ int cnt[NBMAX];
  __shared__ int2 slab[NBMAX * CAPB];
  int t = threadIdx.x;
  for (int i = t; i < nbuck; i += 1024) cnt[i] = 0;
  __syncthreads();

  for (int base_e = blockIdx.x * 2048; base_e < E; base_e += gridDim.x * 2048) {
    #pragma unroll
    for (int u = 0; u < 2; ++u) {
      int e = base_e + u * 1024 + t;
      if (e < E) {
        int d = idx[e];
        int s = idx[E + e];
        float v = val[e];
        int bb = d >> 7;
        int2 pk = make_int2(s | ((d & 127) << 16), __float_as_int(v));
        int slot = atomicAdd(&cnt[bb], 1);
        if (slot < CAPB) slab[bb * CAPB + slot] = pk;
        else {                               // freak overflow: direct write
          int pos = atomicAdd(&cur[bb], 1);
          out[pos] = pk;
        }
      }
    }
    __syncthreads();
    for (int bb = t; bb < nbuck; bb += 1024) {
      int c = cnt[bb];
      if (c > CAPB) c = CAPB;
      if (c >= 8) {
        int ng = c >> 3;
        int pos = atomicAdd(&cur[bb], ng * 8);
        for (int k = 0; k < ng * 8; ++k) out[pos + k] = slab[bb * CAPB + k];
        int r = c & 7;
        for (int k = 0; k < r; ++k)
          slab[bb * CAPB + k] = slab[bb * CAPB + ng * 8 + k];
        cnt[bb] = r;
      }
    }
    __syncthreads();
  }
  for (int bb = t; bb < nbuck; bb += 1024) {
    int c = cnt[bb];
    if (c > CAPB) c = CAPB;
    if (c > 0) {
      int pos = atomicAdd(&cur[bb], c);
      for (int k = 0; k < c; ++k) out[pos + k] = slab[bb * CAPB + k];
    }
  }
}

// Stage 4: one block per bucket -> exact per-dst CSR (rowptr + final edges).
__global__ __launch_bounds__(256) void bucket_to_csr(
    const int2* __restrict__ edgesB, const int* __restrict__ bbase,
    int* __restrict__ rowptr, int2* __restrict__ edges, int N, int E, int nbuck)
{
  int mp = blockIdx.y;
  int b = blockIdx.x;
  int base = bbase[mp * nbuck + b];
  int endp = (b + 1 < nbuck) ? bbase[mp * nbuck + b + 1] : E;
  int cntE = endp - base;
  const int2* in = edgesB + (size_t)mp * E + base;
  int2* out = edges + (size_t)mp * E;

  __shared__ int h[128], csum[128];
  int t = threadIdx.x;
  if (t < 128) h[t] = 0;
  __syncthreads();
  for (int k = t; k < cntE; k += 256)
    atomicAdd(&h[(in[k].x >> 16) & 127], 1);
  __syncthreads();
  if (t == 0) {
    int acc = 0;
    for (int i = 0; i < 128; ++i) { int c = h[i]; csum[i] = acc; acc += c; }
  }
  __syncthreads();
  int d0 = b << 7;
  if (t < 128 && d0 + t < N) rowptr[mp * (N + 1) + d0 + t] = base + csum[t];
  if (t < 128) h[t] = csum[t];   // reuse as per-dst cursor
  __syncthreads();
  for (int k = t; k < cntE; k += 256) {
    int2 pk = in[k];
    int dl = (pk.x >> 16) & 127;
    int pos = atomicAdd(&h[dl], 1);
    out[base + pos] = make_int2(pk.x & 0xFFFF, pk.y);
  }
}

// one wave per dst node: gather rows of h (shared per side) + fp32 accumulate
// -> raw bf16 aggregate. agg = A_sp @ h; the dense GEMM applies W/bias/PReLU.
// At the random-gather BW ceiling (~4 TB/s L2-miss path) — proven round 5-7.
__global__ __launch_bounds__(256) void spmm_csr(
    const u16* __restrict__ hbf, const int* __restrict__ rowptrAll,
    const int2* __restrict__ edgesAll, u16* __restrict__ aggAll,
    int N, int E, size_t NH)
{
  int mp = blockIdx.y;
  const u16* fts = hbf + (size_t)(mp >> 1) * NH;
  const int* rowptr = rowptrAll + (size_t)mp * (N + 1);
  const int2* edges = edgesAll + (size_t)mp * E;
  u16* agg = aggAll + (size_t)mp * NH;

  int gw = (int)((blockIdx.x * 256 + threadIdx.x) >> 6);
  if (gw >= N) return;
  int lane = threadIdx.x & 63;
  int beg = rowptr[gw], end = rowptr[gw + 1];
  float a0 = 0.f, a1 = 0.f, a2 = 0.f, a3 = 0.f;
  for (int base = beg; base < end; base += 64) {
    int k = base + lane;
    int2 ev = make_int2(0, 0);
    if (k < end) ev = edges[k];
    int cnt = min(64, end - base);
    int j = 0;
    for (; j + 8 <= cnt; j += 8) {
      int sj[8]; float vj[8]; ushort4 r[8];
      #pragma unroll
      for (int u = 0; u < 8; ++u) {
        sj[u] = __shfl(ev.x, j + u);
        vj[u] = __uint_as_float((unsigned)__shfl(ev.y, j + u));
      }
      #pragma unroll
      for (int u = 0; u < 8; ++u)
        r[u] = *(const ushort4*)(fts + (size_t)sj[u] * H + lane * 4);
      #pragma unroll
      for (int u = 0; u < 8; ++u) {
        a0 += vj[u] * bf2f(r[u].x);
        a1 += vj[u] * bf2f(r[u].y);
        a2 += vj[u] * bf2f(r[u].z);
        a3 += vj[u] * bf2f(r[u].w);
      }
    }
    for (; j + 4 <= cnt; j += 4) {
      int sj[4]; float vj[4]; ushort4 r[4];
      #pragma unroll
      for (int u = 0; u < 4; ++u) {
        sj[u] = __shfl(ev.x, j + u);
        vj[u] = __uint_as_float((unsigned)__shfl(ev.y, j + u));
      }
      #pragma unroll
      for (int u = 0; u < 4; ++u)
        r[u] = *(const ushort4*)(fts + (size_t)sj[u] * H + lane * 4);
      #pragma unroll
      for (int u = 0; u < 4; ++u) {
        a0 += vj[u] * bf2f(r[u].x);
        a1 += vj[u] * bf2f(r[u].y);
        a2 += vj[u] * bf2f(r[u].z);
        a3 += vj[u] * bf2f(r[u].w);
      }
    }
    for (; j < cnt; ++j) {
      int sj = __shfl(ev.x, j);
      float vj = __uint_as_float((unsigned)__shfl(ev.y, j));
      ushort4 r = *(const ushort4*)(fts + (size_t)sj * H + lane * 4);
      a0 += vj * bf2f(r.x);
      a1 += vj * bf2f(r.y);
      a2 += vj * bf2f(r.z);
      a3 += vj * bf2f(r.w);
    }
  }
  int c = lane * 4;
  *(ushort4*)(agg + (size_t)gw * H + c) =
      make_ushort4(f2bf(a0), f2bf(a1), f2bf(a2), f2bf(a3));
}

// ============== GEMM, BN=256 full-width blocks (A staged once) ===============
// MODE 0: A = agg[pi], W = Wbf[pi], epilogue bias[pi]+PReLU(alpha[pi]) -> e[pi]
// MODE 1: A = eAll[pi], W = WbaseFC[pi>>1], bias fcb[pi>>1], colsum -> sp + pi*H
template <int MODE>
__global__ __launch_bounds__(256) void gemm_bt(
    const u16* __restrict__ Abase, const u16* __restrict__ Wbase,
    u16* __restrict__ Cbase,
    const float* bp0, const float* bp1, const float* bp2, const float* bp3,
    const float* ap0, const float* ap1, const float* ap2, const float* ap3,
    float* __restrict__ colsum, int M, size_t NH)
{
  const int pi = blockIdx.z;
  const float* bps[4] = {bp0, bp1, bp2, bp3};
  const float* aps[4] = {ap0, ap1, ap2, ap3};
  const u16* A = Abase + (size_t)pi * NH;
  const u16* W;
  u16* C = nullptr;
  const float* bias;
  float* cs = nullptr;
  float al = 0.f;
  if (MODE == 0) {
    W = Wbase + (size_t)pi * (H * H);
    C = Cbase + (size_t)pi * NH;
    bias = bps[pi];
    al = aps[pi][0];
  } else {
    W = Wbase + (size_t)(pi >> 1) * (H * H);
    bias = (pi >> 1) ? bp1 : bp0;
    cs = colsum + (size_t)pi * H;
  }

  __shared__ u16 As[128 * 64];   // 16 KB: 128 m-rows x 64 k
  __shared__ u16 Bs[256 * 64];   // 32 KB: 256 n-rows x 64 k
  const int tid  = threadIdx.x;
  const int lane = tid & 63;
  const int wave = tid >> 6;
  const int quad = lane >> 4;
  const int l15  = lane & 15;
  const int m0 = blockIdx.x * 128;
  const int wr = (wave & 1) * 64;     // m-offset of wave
  const int wc = (wave >> 1) * 128;   // n-offset of wave (0 or 128)

  f32x4 acc[4][8] = {};

  for (int k0 = 0; k0 < H; k0 += 64) {
    #pragma unroll
    for (int r = 0; r < 4; ++r) {
      int chunk = r * 256 + tid;
      int row = chunk >> 3;
      int col = (chunk & 7) * 8;
      int gm = m0 + row; if (gm >= M) gm = M - 1;
      async16(A + (size_t)gm * H + k0 + col, As + (r * 256 + wave * 64) * 8);
    }
    #pragma unroll
    for (int r = 0; r < 8; ++r) {
      int chunk = r * 256 + tid;
      int row = chunk >> 3;          // 0..255: full W
      int col = (chunk & 7) * 8;
      async16(W + (size_t)row * H + k0 + col, Bs + (r * 256 + wave * 64) * 8);
    }
    __syncthreads();
    #pragma unroll
    for (int kk = 0; kk < 64; kk += 32) {
      short8 af[4], bf[8];
      #pragma unroll
      for (int i = 0; i < 4; ++i)
        af[i] = *(const short8*)(As + (wr + i * 16 + l15) * 64 + kk + quad * 8);
      #pragma unroll
      for (int i = 0; i < 8; ++i)
        bf[i] = *(const short8*)(Bs + (wc + i * 16 + l15) * 64 + kk + quad * 8);
      #pragma unroll
      for (int mi = 0; mi < 4; ++mi)
        #pragma unroll
        for (int ni = 0; ni < 8; ++ni)
          acc[mi][ni] = __builtin_amdgcn_mfma_f32_16x16x32_bf16(af[mi], bf[ni], acc[mi][ni], 0, 0, 0);
    }
    __syncthreads();
  }

  if (MODE == 0) {
    #pragma unroll
    for (int mi = 0; mi < 4; ++mi)
      #pragma unroll
      for (int ni = 0; ni < 8; ++ni) {
        int n = wc + ni * 16 + l15;
        float bv = bias[n];
        #pragma unroll
        for (int j = 0; j < 4; ++j) {
          int m = m0 + wr + mi * 16 + quad * 4 + j;
          if (m < M) {
            float x = acc[mi][ni][j] + bv;
            x = x > 0.f ? x : al * x;
            C[(size_t)m * H + n] = f2bf(x);
          }
        }
      }
  } else {
    #pragma unroll
    for (int ni = 0; ni < 8; ++ni) {
      int n = wc + ni * 16 + l15;
      float bv = bias[n];
      float s = 0.f;
      #pragma unroll
      for (int mi = 0; mi < 4; ++mi)
        #pragma unroll
        for (int j = 0; j < 4; ++j) {
          int m = m0 + wr + mi * 16 + quad * 4 + j;
          if (m < M) {
            float x = acc[mi][ni][j] + bv;
            s += 1.f - 2.f / (__expf(2.f * x) + 1.f);
          }
        }
      s += __shfl_xor(s, 16);
      s += __shfl_xor(s, 32);
      if (lane < 16) unsafeAtomicAdd(&cs[n], s);
    }
  }
}

// batched over both sides via blockIdx.y; beta computed inline per block
__global__ __launch_bounds__(256) void fuse_out(
    const u16* __restrict__ eAll, const float* __restrict__ sp,
    const float* attd, const float* attp, float invN,
    float* __restrict__ out, int total, size_t NH)
{
  __shared__ float red0[4], red1[4];
  __shared__ float sb0, sb1;
  int s = blockIdx.y;
  int t = threadIdx.x;
  // inline beta (redundant per block; deterministic)
  const float* att = s ? attp : attd;
  const float* spb = sp + (size_t)(2 * s) * H;
  float a = att[t];
  float s0 = spb[t] * invN * a;
  float s1 = spb[H + t] * invN * a;
  #pragma unroll
  for (int off = 32; off > 0; off >>= 1) {
    s0 += __shfl_down(s0, off);
    s1 += __shfl_down(s1, off);
  }
  int lane = t & 63, w = t >> 6;
  if (lane == 0) { red0[w] = s0; red1[w] = s1; }
  __syncthreads();
  if (t == 0) {
    float a0 = red0[0] + red0[1] + red0[2] + red0[3];
    float a1 = red1[0] + red1[1] + red1[2] + red1[3];
    float mx = fmaxf(a0, a1);
    float e0v = __expf(a0 - mx), e1v = __expf(a1 - mx);
    float inv = 1.f / (e0v + e1v);
    sb0 = e0v * inv;
    sb1 = e1v * inv;
  }
  __syncthreads();
  float b0 = sb0, b1 = sb1;

  const u16* e0 = eAll + (size_t)(2 * s) * NH;
  const u16* e1 = eAll + (size_t)(2 * s + 1) * NH;
  float* o = out + (size_t)s * NH;
  int i = (blockIdx.x * 256 + t) * 4;
  if (i >= total) return;
  ushort4 u0 = *(const ushort4*)(e0 + i);
  ushort4 u1 = *(const ushort4*)(e1 + i);
  float4 ov;
  ov.x = b0 * bf2f(u0.x) + b1 * bf2f(u1.x);
  ov.y = b0 * bf2f(u0.y) + b1 * bf2f(u1.y);
  ov.z = b0 * bf2f(u0.z) + b1 * bf2f(u1.z);
  ov.w = b0 * bf2f(u0.w) + b1 * bf2f(u1.w);
  *(float4*)(o + i) = ov;
}

extern "C" void kernel_launch(void* const* d_in, const int* in_sizes, int n_in,
                              void* d_out, int out_size, void* d_ws, size_t ws_size,
                              hipStream_t stream)
{
  const float* h_in[2] = {(const float*)d_in[0], (const float*)d_in[1]};
  const int N = in_sizes[0] / H;      // 50000
  const int E = in_sizes[3];          // 800000
  const int* idx[4]; const float* val[4];
  for (int i = 0; i < 4; ++i) {
    idx[i] = (const int*)d_in[2 + 2 * i];
    val[i] = (const float*)d_in[3 + 2 * i];
  }
  const float *W[4], *bia[4], *alp[4];
  for (int i = 0; i < 4; ++i) {
    W[i]   = (const float*)d_in[10 + 3 * i];
    bia[i] = (const float*)d_in[11 + 3 * i];
    alp[i] = (const float*)d_in[12 + 3 * i];
  }
  const float *fcW[2], *fcb[2], *att[2];
  for (int s = 0; s < 2; ++s) {
    fcW[s] = (const float*)d_in[22 + 3 * s];
    fcb[s] = (const float*)d_in[23 + 3 * s];
    att[s] = (const float*)d_in[24 + 3 * s];
  }

  const size_t NH = (size_t)N * H;
  const int nbuck = (N + 127) >> 7;   // 391 (must be <= NBMAX)
  auto align256 = [](size_t x) { return (x + 255) & ~(size_t)255; };
  char* p = (char*)d_ws;
  u16* hbf = (u16*)p;      p += align256((size_t)2 * NH * 2);   // 51.2 MB (both sides)
  u16* aggAll = (u16*)p;   p += align256((size_t)4 * NH * 2);   // 102.4 MB (A_sp@h per metapath; edgesB aliases)
  u16* eAll = (u16*)p;     p += align256((size_t)4 * NH * 2);   // 102.4 MB (4 metapath embeds)
  u16* Wbf = (u16*)p;      p += align256((size_t)6 * H * H * 2);
  int* bcnt = (int*)p;     p += align256((size_t)4 * NBMAX * 4);
  int* bbase = (int*)p;    p += align256((size_t)4 * NBMAX * 4);
  int* gcur = (int*)p;     p += align256((size_t)4 * NBMAX * 4);
  int* rowptr = (int*)p;   p += align256((size_t)4 * (N + 1) * 4);
  int2* edges = (int2*)p;  p += align256((size_t)4 * E * 8);    // 25.6 MB
  float* sp = (float*)p;
  int2* edgesB = (int2*)aggAll;  // aggAll dead during CSR build (4*E*8 <= 4*NH*2)

  const int gx = (N + 127) / 128;
  const int tot = (int)NH;
  const int el_blocks = (tot / 4 + 255) / 256;   // 12500
  const int spmm_blocks = (N + 3) / 4;

  // fused prep: h->bf16, weights->bf16, zero bcnt/sp
  prep<<<dim3(el_blocks, 3), 256, 0, stream>>>(
      h_in[0], h_in[1], hbf,
      W[0], W[1], W[2], W[3], fcW[0], fcW[1], Wbf,
      bcnt, sp, tot, NH);

  // ---- bucketed CSR build for all 4 metapaths ----
  hist_coarse<<<dim3(64, 4), 1024, 0, stream>>>(idx[0], idx[1], idx[2], idx[3],
                                                bcnt, E, nbuck);
  scan_buckets<<<dim3(1, 4), 256, 0, stream>>>(bcnt, bbase, gcur, rowptr, N, E, nbuck);
  scatter_binned<<<dim3(64, 4), 1024, 0, stream>>>(idx[0], idx[1], idx[2], idx[3],
                                                   val[0], val[1], val[2], val[3],
                                                   gcur, edgesB, E, nbuck);
  bucket_to_csr<<<dim3(nbuck, 4), 256, 0, stream>>>(edgesB, bbase, rowptr, edges,
                                                    N, E, nbuck);

  // agg[pi] = A_sp[pi] @ h[side]
  spmm_csr<<<dim3(spmm_blocks, 4), 256, 0, stream>>>(
      hbf, rowptr, edges, aggAll, N, E, NH);

  // e[pi] = PReLU(agg[pi] @ W[pi]^T + b[pi])
  gemm_bt<0><<<dim3(gx, 1, 4), 256, 0, stream>>>(
      aggAll, Wbf, eAll,
      bia[0], bia[1], bia[2], bia[3],
      alp[0], alp[1], alp[2], alp[3],
      nullptr, N, NH);

  // sp[pi] = colsum(tanh(e[pi] @ fcW[side]^T + fcb[side]))
  gemm_bt<1><<<dim3(gx, 1, 4), 256, 0, stream>>>(
      eAll, Wbf + (size_t)4 * H * H, nullptr,
      fcb[0], fcb[1], nullptr, nullptr,
      nullptr, nullptr, nullptr, nullptr,
      sp, N, NH);

  // z[side] = beta0*e0 + beta1*e1 (beta computed inline from sp)
  fuse_out<<<dim3(el_blocks, 2), 256, 0, stream>>>(
      eAll, sp, att[0], att[1], 1.0f / (float)N, (float*)d_out, tot, NH);
}

// Round 9
// 688.496 us; speedup vs baseline: 1.2637x; 1.2637x over previous
//
#include <hip/hip_runtime.h>
#include <cstdint>

#define H 256
#define NBMAX 400   // max coarse buckets per metapath (supports N <= 51200)
#define CAPB 16     // LDS slab slots per bucket (flush in groups of 8)

typedef unsigned short u16;
typedef __attribute__((ext_vector_type(8))) short short8;
typedef __attribute__((ext_vector_type(4))) float f32x4;

__device__ __forceinline__ float bf2f(u16 u) {
  return __uint_as_float(((unsigned)u) << 16);
}
__device__ __forceinline__ u16 f2bf(float f) {
  unsigned u = __float_as_uint(f);
  u = (u + 0x7FFF + ((u >> 16) & 1)) >> 16;   // RNE
  return (u16)u;
}
__device__ __forceinline__ void async16(const void* g, void* l) {
  __builtin_amdgcn_global_load_lds((const __attribute__((address_space(1))) void*)g,
                                   (__attribute__((address_space(3))) void*)l, 16, 0, 0);
}

// ---- fused prep: h->bf16 (both sides) + weights->bf16 + zero bcnt/sp ----
// grid (el_blocks, 3): y<2 = side conversion; y==2: x<384 weights, x==384 zeroing
__global__ __launch_bounds__(256) void prep(
    const float* __restrict__ h0, const float* __restrict__ h1,
    u16* __restrict__ hbf,
    const float* w0, const float* w1, const float* w2, const float* w3,
    const float* w4, const float* w5, u16* __restrict__ Wbf,
    int* __restrict__ bcnt, float* __restrict__ sp, int total, size_t NH)
{
  int y = blockIdx.y;
  int tid = threadIdx.x;
  if (y < 2) {
    const float* src = y ? h1 : h0;
    u16* d = hbf + (size_t)y * NH;
    int i = (blockIdx.x * 256 + tid) * 4;
    if (i >= total) return;
    float4 x = *(const float4*)(src + i);
    *(ushort4*)(d + i) = make_ushort4(f2bf(x.x), f2bf(x.y), f2bf(x.z), f2bf(x.w));
  } else {
    int x = blockIdx.x;
    if (x < 384) {
      const float* srcs[6] = {w0, w1, w2, w3, w4, w5};
      int m = x >> 6;
      int i = ((x & 63) * 256 + tid) * 4;
      float4 v = *(const float4*)(srcs[m] + i);
      *(ushort4*)(Wbf + (size_t)m * (H * H) + i) =
          make_ushort4(f2bf(v.x), f2bf(v.y), f2bf(v.z), f2bf(v.w));
    } else if (x == 384) {
      for (int i = tid; i < 4 * NBMAX; i += 256) bcnt[i] = 0;
      for (int i = tid; i < 4 * H; i += 256) sp[i] = 0.f;
    }
  }
}

__device__ __forceinline__ int block_incl_scan(int v) {
  __shared__ int wsum[4];
  int tid = threadIdx.x, lane = tid & 63, w = tid >> 6;
  int x = v;
  #pragma unroll
  for (int off = 1; off < 64; off <<= 1) {
    int n = __shfl_up(x, off);
    if (lane >= off) x += n;
  }
  if (lane == 63) wsum[w] = x;
  __syncthreads();
  int add = 0;
  #pragma unroll
  for (int i = 0; i < 4; ++i) add += (i < w) ? wsum[i] : 0;
  return x + add;
}

// ============ Bucketed CSR build (bucket = 128 consecutive dsts) =============
__global__ __launch_bounds__(1024) void hist_coarse(
    const int* i0, const int* i1, const int* i2, const int* i3,
    int* __restrict__ bcnt, int E, int nbuck)
{
  int mp = blockIdx.y;
  const int* idxs[4] = {i0, i1, i2, i3};
  const int* idx = idxs[mp];
  __shared__ int lh[NBMAX];
  int t = threadIdx.x;
  for (int i = t; i < nbuck; i += 1024) lh[i] = 0;
  __syncthreads();
  for (int e = blockIdx.x * 1024 + t; e < E; e += gridDim.x * 1024)
    atomicAdd(&lh[idx[e] >> 7], 1);
  __syncthreads();
  for (int i = t; i < nbuck; i += 1024) {
    int v = lh[i];
    if (v) atomicAdd(&bcnt[mp * nbuck + i], v);
  }
}

__global__ __launch_bounds__(256) void scan_buckets(
    const int* __restrict__ bcnt, int* __restrict__ bbase,
    int* __restrict__ gcur, int* __restrict__ rowptr, int N, int E, int nbuck)
{
  int mp = blockIdx.y;
  int t = threadIdx.x;
  int i0 = t * 2, i1 = t * 2 + 1;
  int a = (i0 < nbuck) ? bcnt[mp * nbuck + i0] : 0;
  int b = (i1 < nbuck) ? bcnt[mp * nbuck + i1] : 0;
  int s = a + b;
  int incl = block_incl_scan(s);
  int ex = incl - s;
  if (i0 < nbuck) { bbase[mp * nbuck + i0] = ex;     gcur[mp * nbuck + i0] = ex; }
  if (i1 < nbuck) { bbase[mp * nbuck + i1] = ex + a; gcur[mp * nbuck + i1] = ex + a; }
  if (t == 0) rowptr[mp * (N + 1) + N] = E;
}

// Stage 3: LDS write-combining scatter into bucket-contiguous staging.
__global__ __launch_bounds__(1024) void scatter_binned(
    const int* i0, const int* i1, const int* i2, const int* i3,
    const float* v0, const float* v1, const float* v2, const float* v3,
    int* __restrict__ gcur, int2* __restrict__ edgesB, int E, int nbuck)
{
  int mp = blockIdx.y;
  const int* idxs[4] = {i0, i1, i2, i3};
  const float* vals[4] = {v0, v1, v2, v3};
  const int* idx = idxs[mp];
  const float* val = vals[mp];
  int* cur = gcur + mp * nbuck;
  int2* out = edgesB + (size_t)mp * E;

  __shared__ int cnt[NBMAX];
  __shared__ int2 slab[NBMAX * CAPB];
  int t = threadIdx.x;
  for (int i = t; i < nbuck; i += 1024) cnt[i] = 0;
  __syncthreads();

  for (int base_e = blockIdx.x * 2048; base_e < E; base_e += gridDim.x * 2048) {
    #pragma unroll
    for (int u = 0; u < 2; ++u) {
      int e = base_e + u * 1024 + t;
      if (e < E) {
        int d = idx[e];
        int s = idx[E + e];
        float v = val[e];
        int bb = d >> 7;
        int2 pk = make_int2(s | ((d & 127) << 16), __float_as_int(v));
        int slot = atomicAdd(&cnt[bb], 1);
        if (slot < CAPB) slab[bb * CAPB + slot] = pk;
        else {                               // freak overflow: direct write
          int pos = atomicAdd(&cur[bb], 1);
          out[pos] = pk;
        }
      }
    }
    __syncthreads();
    for (int bb = t; bb < nbuck; bb += 1024) {
      int c = cnt[bb];
      if (c > CAPB) c = CAPB;
      if (c >= 8) {
        int ng = c >> 3;
        int pos = atomicAdd(&cur[bb], ng * 8);
        for (int k = 0; k < ng * 8; ++k) out[pos + k] = slab[bb * CAPB + k];
        int r = c & 7;
        for (int k = 0; k < r; ++k)
          slab[bb * CAPB + k] = slab[bb * CAPB + ng * 8 + k];
        cnt[bb] = r;
      }
    }
    __syncthreads();
  }
  for (int bb = t; bb < nbuck; bb += 1024) {
    int c = cnt[bb];
    if (c > CAPB) c = CAPB;
    if (c > 0) {
      int pos = atomicAdd(&cur[bb], c);
      for (int k = 0; k < c; ++k) out[pos + k] = slab[bb * CAPB + k];
    }
  }
}

// Stage 4: one block per bucket -> exact per-dst CSR (rowptr + final edges).
__global__ __launch_bounds__(256) void bucket_to_csr(
    const int2* __restrict__ edgesB, const int* __restrict__ bbase,
    int* __restrict__ rowptr, int2* __restrict__ edges, int N, int E, int nbuck)
{
  int mp = blockIdx.y;
  int b = blockIdx.x;
  int base = bbase[mp * nbuck + b];
  int endp = (b + 1 < nbuck) ? bbase[mp * nbuck + b + 1] : E;
  int cntE = endp - base;
  const int2* in = edgesB + (size_t)mp * E + base;
  int2* out = edges + (size_t)mp * E;

  __shared__ int h[128], csum[128];
  int t = threadIdx.x;
  if (t < 128) h[t] = 0;
  __syncthreads();
  for (int k = t; k < cntE; k += 256)
    atomicAdd(&h[(in[k].x >> 16) & 127], 1);
  __syncthreads();
  if (t == 0) {
    int acc = 0;
    for (int i = 0; i < 128; ++i) { int c = h[i]; csum[i] = acc; acc += c; }
  }
  __syncthreads();
  int d0 = b << 7;
  if (t < 128 && d0 + t < N) rowptr[mp * (N + 1) + d0 + t] = base + csum[t];
  if (t < 128) h[t] = csum[t];   // reuse as per-dst cursor
  __syncthreads();
  for (int k = t; k < cntE; k += 256) {
    int2 pk = in[k];
    int dl = (pk.x >> 16) & 127;
    int pos = atomicAdd(&h[dl], 1);
    out[base + pos] = make_int2(pk.x & 0xFFFF, pk.y);
  }
}

// one wave per dst node: gather + fp32 accumulate + fused bias/PReLU -> bf16
// round-4-proven loop; batched over metapaths via blockIdx.y
__global__ __launch_bounds__(256) void spmm_csr(
    const u16* __restrict__ ftsAll, const int* __restrict__ rowptrAll,
    const int2* __restrict__ edgesAll,
    const float* b0, const float* b1, const float* b2, const float* b3,
    const float* a0ptr, const float* a1ptr, const float* a2ptr, const float* a3ptr,
    u16* __restrict__ eAll, int N, int E, size_t NH)
{
  int mp = blockIdx.y;
  const u16* fts = ftsAll + (size_t)mp * NH;
  const int* rowptr = rowptrAll + (size_t)mp * (N + 1);
  const int2* edges = edgesAll + (size_t)mp * E;
  const float* biases[4] = {b0, b1, b2, b3};
  const float* alphas[4] = {a0ptr, a1ptr, a2ptr, a3ptr};
  const float* bias = biases[mp];
  const float* alpha = alphas[mp];
  u16* e = eAll + (size_t)mp * NH;

  int gw = (int)((blockIdx.x * 256 + threadIdx.x) >> 6);
  if (gw >= N) return;
  int lane = threadIdx.x & 63;
  int beg = rowptr[gw], end = rowptr[gw + 1];
  float a0 = 0.f, a1 = 0.f, a2 = 0.f, a3 = 0.f;
  for (int base = beg; base < end; base += 64) {
    int k = base + lane;
    int2 ev = make_int2(0, 0);
    if (k < end) ev = edges[k];
    int cnt = min(64, end - base);
    int j = 0;
    for (; j + 4 <= cnt; j += 4) {
      int sj[4]; float vj[4]; ushort4 r[4];
      #pragma unroll
      for (int u = 0; u < 4; ++u) {
        sj[u] = __shfl(ev.x, j + u);
        vj[u] = __uint_as_float((unsigned)__shfl(ev.y, j + u));
      }
      #pragma unroll
      for (int u = 0; u < 4; ++u)
        r[u] = *(const ushort4*)(fts + (size_t)sj[u] * H + lane * 4);
      #pragma unroll
      for (int u = 0; u < 4; ++u) {
        a0 += vj[u] * bf2f(r[u].x);
        a1 += vj[u] * bf2f(r[u].y);
        a2 += vj[u] * bf2f(r[u].z);
        a3 += vj[u] * bf2f(r[u].w);
      }
    }
    for (; j < cnt; ++j) {
      int sj = __shfl(ev.x, j);
      float vj = __uint_as_float((unsigned)__shfl(ev.y, j));
      ushort4 r = *(const ushort4*)(fts + (size_t)sj * H + lane * 4);
      a0 += vj * bf2f(r.x);
      a1 += vj * bf2f(r.y);
      a2 += vj * bf2f(r.z);
      a3 += vj * bf2f(r.w);
    }
  }
  int c = lane * 4;
  float al = alpha[0];
  float r0 = a0 + bias[c],     r1 = a1 + bias[c + 1];
  float r2 = a2 + bias[c + 2], r3 = a3 + bias[c + 3];
  r0 = r0 > 0.f ? r0 : al * r0;
  r1 = r1 > 0.f ? r1 : al * r1;
  r2 = r2 > 0.f ? r2 : al * r2;
  r3 = r3 > 0.f ? r3 : al * r3;
  *(ushort4*)(e + (size_t)gw * H + c) =
      make_ushort4(f2bf(r0), f2bf(r1), f2bf(r2), f2bf(r3));
}

// ================= GEMM (m97 structure), batched via blockIdx.z ===============
// MODE 0: A = hbf[pi>>1], W = Wbf[pi], C = fts[pi]
// MODE 1: A = eAll[pi], W = WbaseFC[pi>>1], colsum -> sp + pi*H
template <int MODE>
__global__ __launch_bounds__(256) void gemm_bt(
    const u16* __restrict__ Abase, const u16* __restrict__ Wbase,
    u16* __restrict__ Cbase, const float* fcb0, const float* fcb1,
    float* __restrict__ colsum, int M, size_t NH)
{
  const int pi = blockIdx.z;
  const u16* A; const u16* W; u16* C = nullptr;
  const float* bias = nullptr; float* cs = nullptr;
  if (MODE == 0) {
    A = Abase + (size_t)(pi >> 1) * NH;
    W = Wbase + (size_t)pi * (H * H);
    C = Cbase + (size_t)pi * NH;
  } else {
    A = Abase + (size_t)pi * NH;
    W = Wbase + (size_t)(pi >> 1) * (H * H);
    bias = (pi >> 1) ? fcb1 : fcb0;
    cs = colsum + (size_t)pi * H;
  }

  __shared__ u16 As[128 * 64];
  __shared__ u16 Bs[128 * 64];
  const int tid  = threadIdx.x;
  const int lane = tid & 63;
  const int wave = tid >> 6;
  const int quad = lane >> 4;
  const int l15  = lane & 15;
  const int m0 = blockIdx.x * 128;
  const int n0 = blockIdx.y * 128;
  const int wr = (wave & 1) * 64;
  const int wc = (wave >> 1) * 64;

  f32x4 acc[4][4] = {};

  for (int k0 = 0; k0 < H; k0 += 64) {
    #pragma unroll
    for (int r = 0; r < 4; ++r) {
      int chunk = r * 256 + tid;
      int row = chunk >> 3;
      int col = (chunk & 7) * 8;
      int gm = m0 + row; if (gm >= M) gm = M - 1;
      u16* lbase = As + (r * 256 + wave * 64) * 8;
      async16(A + (size_t)gm * H + k0 + col, lbase);
      u16* lbase2 = Bs + (r * 256 + wave * 64) * 8;
      async16(W + (size_t)(n0 + row) * H + k0 + col, lbase2);
    }
    __syncthreads();
    #pragma unroll
    for (int kk = 0; kk < 64; kk += 32) {
      short8 af[4], bf[4];
      #pragma unroll
      for (int i = 0; i < 4; ++i) {
        af[i] = *(const short8*)(As + (wr + i * 16 + l15) * 64 + kk + quad * 8);
        bf[i] = *(const short8*)(Bs + (wc + i * 16 + l15) * 64 + kk + quad * 8);
      }
      #pragma unroll
      for (int mi = 0; mi < 4; ++mi)
        #pragma unroll
        for (int ni = 0; ni < 4; ++ni)
          acc[mi][ni] = __builtin_amdgcn_mfma_f32_16x16x32_bf16(af[mi], bf[ni], acc[mi][ni], 0, 0, 0);
    }
    __syncthreads();
  }

  if (MODE == 0) {
    #pragma unroll
    for (int mi = 0; mi < 4; ++mi)
      #pragma unroll
      for (int ni = 0; ni < 4; ++ni) {
        int n = n0 + wc + ni * 16 + l15;
        #pragma unroll
        for (int j = 0; j < 4; ++j) {
          int m = m0 + wr + mi * 16 + quad * 4 + j;
          if (m < M) C[(size_t)m * H + n] = f2bf(acc[mi][ni][j]);
        }
      }
  } else {
    #pragma unroll
    for (int ni = 0; ni < 4; ++ni) {
      int n = n0 + wc + ni * 16 + l15;
      float bv = bias[n];
      float s = 0.f;
      #pragma unroll
      for (int mi = 0; mi < 4; ++mi)
        #pragma unroll
        for (int j = 0; j < 4; ++j) {
          int m = m0 + wr + mi * 16 + quad * 4 + j;
          if (m < M) {
            float x = acc[mi][ni][j] + bv;
            s += 1.f - 2.f / (__expf(2.f * x) + 1.f);
          }
        }
      s += __shfl_xor(s, 16);
      s += __shfl_xor(s, 32);
      if (lane < 16) unsafeAtomicAdd(&cs[n], s);
    }
  }
}

// batched over both sides via blockIdx.y; beta computed inline per block
__global__ __launch_bounds__(256) void fuse_out(
    const u16* __restrict__ eAll, const float* __restrict__ sp,
    const float* attd, const float* attp, float invN,
    float* __restrict__ out, int total, size_t NH)
{
  __shared__ float red0[4], red1[4];
  __shared__ float sb0, sb1;
  int s = blockIdx.y;
  int t = threadIdx.x;
  // inline beta (redundant per block; deterministic)
  const float* att = s ? attp : attd;
  const float* spb = sp + (size_t)(2 * s) * H;
  float a = att[t];
  float s0 = spb[t] * invN * a;
  float s1 = spb[H + t] * invN * a;
  #pragma unroll
  for (int off = 32; off > 0; off >>= 1) {
    s0 += __shfl_down(s0, off);
    s1 += __shfl_down(s1, off);
  }
  int lane = t & 63, w = t >> 6;
  if (lane == 0) { red0[w] = s0; red1[w] = s1; }
  __syncthreads();
  if (t == 0) {
    float a0 = red0[0] + red0[1] + red0[2] + red0[3];
    float a1 = red1[0] + red1[1] + red1[2] + red1[3];
    float mx = fmaxf(a0, a1);
    float e0v = __expf(a0 - mx), e1v = __expf(a1 - mx);
    float inv = 1.f / (e0v + e1v);
    sb0 = e0v * inv;
    sb1 = e1v * inv;
  }
  __syncthreads();
  float b0 = sb0, b1 = sb1;

  const u16* e0 = eAll + (size_t)(2 * s) * NH;
  const u16* e1 = eAll + (size_t)(2 * s + 1) * NH;
  float* o = out + (size_t)s * NH;
  int i = (blockIdx.x * 256 + t) * 4;
  if (i >= total) return;
  ushort4 u0 = *(const ushort4*)(e0 + i);
  ushort4 u1 = *(const ushort4*)(e1 + i);
  float4 ov;
  ov.x = b0 * bf2f(u0.x) + b1 * bf2f(u1.x);
  ov.y = b0 * bf2f(u0.y) + b1 * bf2f(u1.y);
  ov.z = b0 * bf2f(u0.z) + b1 * bf2f(u1.z);
  ov.w = b0 * bf2f(u0.w) + b1 * bf2f(u1.w);
  *(float4*)(o + i) = ov;
}

extern "C" void kernel_launch(void* const* d_in, const int* in_sizes, int n_in,
                              void* d_out, int out_size, void* d_ws, size_t ws_size,
                              hipStream_t stream)
{
  const float* h_in[2] = {(const float*)d_in[0], (const float*)d_in[1]};
  const int N = in_sizes[0] / H;      // 50000
  const int E = in_sizes[3];          // 800000
  const int* idx[4]; const float* val[4];
  for (int i = 0; i < 4; ++i) {
    idx[i] = (const int*)d_in[2 + 2 * i];
    val[i] = (const float*)d_in[3 + 2 * i];
  }
  const float *W[4], *bia[4], *alp[4];
  for (int i = 0; i < 4; ++i) {
    W[i]   = (const float*)d_in[10 + 3 * i];
    bia[i] = (const float*)d_in[11 + 3 * i];
    alp[i] = (const float*)d_in[12 + 3 * i];
  }
  const float *fcW[2], *fcb[2], *att[2];
  for (int s = 0; s < 2; ++s) {
    fcW[s] = (const float*)d_in[22 + 3 * s];
    fcb[s] = (const float*)d_in[23 + 3 * s];
    att[s] = (const float*)d_in[24 + 3 * s];
  }

  const size_t NH = (size_t)N * H;
  const int nbuck = (N + 127) >> 7;   // 391 (must be <= NBMAX)
  auto align256 = [](size_t x) { return (x + 255) & ~(size_t)255; };
  char* p = (char*)d_ws;
  u16* hbf = (u16*)p;      p += align256((size_t)2 * NH * 2);   // 51.2 MB (both sides)
  u16* fts = (u16*)p;      p += align256((size_t)4 * NH * 2);   // 102.4 MB (h@W^T per metapath; edgesB aliases)
  u16* eAll = (u16*)p;     p += align256((size_t)4 * NH * 2);   // 102.4 MB (4 metapath embeds)
  u16* Wbf = (u16*)p;      p += align256((size_t)6 * H * H * 2);
  int* bcnt = (int*)p;     p += align256((size_t)4 * NBMAX * 4);
  int* bbase = (int*)p;    p += align256((size_t)4 * NBMAX * 4);
  int* gcur = (int*)p;     p += align256((size_t)4 * NBMAX * 4);
  int* rowptr = (int*)p;   p += align256((size_t)4 * (N + 1) * 4);
  int2* edges = (int2*)p;  p += align256((size_t)4 * E * 8);    // 25.6 MB
  float* sp = (float*)p;
  int2* edgesB = (int2*)fts;  // fts dead during CSR build (4*E*8 <= 4*NH*2)

  const int gx = (N + 127) / 128;
  const int tot = (int)NH;
  const int el_blocks = (tot / 4 + 255) / 256;   // 12500
  const int spmm_blocks = (N + 3) / 4;

  // fused prep: h->bf16, weights->bf16, zero bcnt/sp
  prep<<<dim3(el_blocks, 3), 256, 0, stream>>>(
      h_in[0], h_in[1], hbf,
      W[0], W[1], W[2], W[3], fcW[0], fcW[1], Wbf,
      bcnt, sp, tot, NH);

  // ---- bucketed CSR build for all 4 metapaths ----
  hist_coarse<<<dim3(64, 4), 1024, 0, stream>>>(idx[0], idx[1], idx[2], idx[3],
                                                bcnt, E, nbuck);
  scan_buckets<<<dim3(1, 4), 256, 0, stream>>>(bcnt, bbase, gcur, rowptr, N, E, nbuck);
  scatter_binned<<<dim3(64, 4), 1024, 0, stream>>>(idx[0], idx[1], idx[2], idx[3],
                                                   val[0], val[1], val[2], val[3],
                                                   gcur, edgesB, E, nbuck);
  bucket_to_csr<<<dim3(nbuck, 4), 256, 0, stream>>>(edgesB, bbase, rowptr, edges,
                                                    N, E, nbuck);

  // fts[pi] = hbf[side] @ W[pi]^T
  gemm_bt<0><<<dim3(gx, 2, 4), 256, 0, stream>>>(hbf, Wbf, fts,
                                                 nullptr, nullptr, nullptr, N, NH);

  // e[pi] = PReLU(A_sp[pi] @ fts[pi] + b[pi])
  spmm_csr<<<dim3(spmm_blocks, 4), 256, 0, stream>>>(
      fts, rowptr, edges,
      bia[0], bia[1], bia[2], bia[3],
      alp[0], alp[1], alp[2], alp[3],
      eAll, N, E, NH);

  // sp[pi] = colsum(tanh(e[pi] @ fcW[side]^T + fcb[side]))
  gemm_bt<1><<<dim3(gx, 2, 4), 256, 0, stream>>>(eAll, Wbf + (size_t)4 * H * H,
                                                 nullptr, fcb[0], fcb[1], sp, N, NH);

  // z[side] = beta0*e0 + beta1*e1 (beta computed inline from sp)
  fuse_out<<<dim3(el_blocks, 2), 256, 0, stream>>>(
      eAll, sp, att[0], att[1], 1.0f / (float)N, (float*)d_out, tot, NH);
}